// Round 6
// baseline (599.159 us; speedup 1.0000x reference)
//
#include <hip/hip_runtime.h>

typedef __attribute__((ext_vector_type(8))) short short8;
typedef __attribute__((ext_vector_type(8))) unsigned short u16x8;
typedef __attribute__((ext_vector_type(4))) float f32x4;

#define NB 4
#define CHN 256
#define NSP 4096
#define PROJD 64
#define NH 4
#define HD 16
#define SL 16384
#define QSCALE 0.36067376022224085f  // SCALE(0.25) * log2(e)

__device__ __forceinline__ float b2f(unsigned short u) {
    union { unsigned ui; float f; } x; x.ui = ((unsigned)u) << 16; return x.f;
}
__device__ __forceinline__ unsigned short f2b(float f) {
    union { float f; unsigned ui; } x; x.f = f;
    unsigned r = x.ui + 0x7fffu + ((x.ui >> 16) & 1u);
    return (unsigned short)(r >> 16);
}
__device__ __forceinline__ unsigned cvtpk(float lo, float hi) {
    unsigned r;
    asm("v_cvt_pk_bf16_f32 %0, %1, %2" : "=v"(r) : "v"(lo), "v"(hi));
    return r;
}
__device__ __forceinline__ short8 mk8(unsigned a, unsigned b, unsigned c, unsigned d) {
    union { unsigned u[4]; short8 v; } x;
    x.u[0] = a; x.u[1] = b; x.u[2] = c; x.u[3] = d;
    return x.v;
}

// Detect underlying dtype of feat buffer: returns 1 if fp32, 0 if bf16.
__device__ __forceinline__ int detect_f32(const unsigned short* fa) {
    const int t = threadIdx.x;
    __shared__ int sflag;
    if (t < 64) {
        int wild = 0;
        #pragma unroll
        for (int e = 0; e < 8; ++e) {
            unsigned short u = fa[(t * 8 + e) * 2];
            int ex = (u >> 7) & 0xFF;
            if (ex != 0 && (ex < 0x6E || ex > 0x8A)) wild++;
        }
        #pragma unroll
        for (int off = 1; off < 64; off <<= 1) wild += __shfl_xor(wild, off);
        if (t == 0) sflag = (wild > 64) ? 1 : 0;
    }
    __syncthreads();
    return sflag;
}

struct P20 { const void* p[20]; };

// ---------------- Kernel 0: canonicalize the 20 param tensors to bf16 slots ----------------
__global__ __launch_bounds__(256) void k_conv(P20 ptrs, const unsigned short* feat_a,
                                              unsigned short* dst) {
    const int isf = detect_f32(feat_a);
    const int id = blockIdx.x;
    const int sizes[20] = {16384,64,16384,64,16384,64,16384,64,16384,64,16384,64,
                           16384,256,16384,256,256,256,256,256};
    const int n = sizes[id];
    unsigned short* o = dst + id * SL;
    if (isf) {
        const float* s = (const float*)ptrs.p[id];
        for (int i = threadIdx.x; i < n; i += 256) o[i] = f2b(s[i]);
    } else {
        const unsigned short* s = (const unsigned short*)ptrs.p[id];
        for (int i = threadIdx.x; i < n; i += 256) o[i] = s[i];
    }
}

// ---------------- Kernel 1: QKV projections ----------------
__global__ __launch_bounds__(256) void k_proj(
    const unsigned short* __restrict__ feat_a, const unsigned short* __restrict__ feat_b,
    const unsigned short* __restrict__ prm,
    unsigned short* __restrict__ Qp, unsigned short* __restrict__ Kp,
    unsigned short* __restrict__ Vp)
{
    const int isf = detect_f32(feat_a);
    const int f = blockIdx.y >> 2;
    const int b = blockIdx.y & 3;
    const int n0 = blockIdx.x * 64;
    const unsigned short* feat = f ? feat_b : feat_a;
    const unsigned short* wq  = prm + (f ? 6 : 0) * SL;
    const unsigned short* biq = prm + (f ? 7 : 1) * SL;
    const unsigned short* wk  = prm + (f ? 2 : 8) * SL;
    const unsigned short* bik = prm + (f ? 3 : 9) * SL;
    const unsigned short* wv  = prm + (f ? 4 : 10) * SL;
    const unsigned short* biv = prm + (f ? 5 : 11) * SL;
    const int sq = f, skv = 1 - f;

    __shared__ unsigned short lds[64 * 40];   // feat^T tile [64 n][32 c], row stride 40 shorts
    const int t = threadIdx.x;
    const int lane = t & 63, w = t >> 6;

    f32x4 acc[12];
    #pragma unroll
    for (int i = 0; i < 12; ++i)
        #pragma unroll
        for (int r = 0; r < 4; ++r) acc[i][r] = 0.f;

    for (int c0 = 0; c0 < CHN; c0 += 32) {
        __syncthreads();
        {
            const int cc = t >> 3, nn = (t & 7) * 8;
            const size_t base = (size_t)(b * CHN + c0 + cc) * NSP + n0 + nn;
            if (isf) {
                const float* ff = (const float*)feat;
                f32x4 v0 = *(const f32x4*)(ff + base);
                f32x4 v1 = *(const f32x4*)(ff + base + 4);
                #pragma unroll
                for (int e = 0; e < 4; ++e) {
                    lds[(nn + e) * 40 + cc] = f2b(v0[e]);
                    lds[(nn + 4 + e) * 40 + cc] = f2b(v1[e]);
                }
            } else {
                u16x8 v = *(const u16x8*)(feat + base);
                #pragma unroll
                for (int e = 0; e < 8; ++e) lds[(nn + e) * 40 + cc] = v[e];
            }
        }
        __syncthreads();
        short8 af = *(const short8*)&lds[(16 * w + (lane & 15)) * 40 + (lane >> 4) * 8];
        #pragma unroll
        for (int mp = 0; mp < 12; ++mp) {
            const unsigned short* W = mp < 4 ? wq : (mp < 8 ? wk : wv);
            const int prow = (mp & 3) * 16 + (lane & 15);
            short8 bf = *(const short8*)(W + prow * CHN + c0 + (lane >> 4) * 8);
            acc[mp] = __builtin_amdgcn_mfma_f32_16x16x32_bf16(af, bf, acc[mp], 0, 0, 0);
        }
    }

    #pragma unroll
    for (int mp = 0; mp < 12; ++mp) {
        const unsigned short* Bi = mp < 4 ? biq : (mp < 8 ? bik : biv);
        const int hh = mp & 3, d = lane & 15;
        const float bias = b2f(Bi[hh * 16 + d]);
        #pragma unroll
        for (int r = 0; r < 4; ++r) {
            const int nrow = n0 + 16 * w + (lane >> 4) * 4 + r;
            float val = acc[mp][r] + bias;
            if (mp < 4) {
                val *= QSCALE;
                Qp[(((sq * NB + b) * NH + hh) * NSP + nrow) * HD + d] = f2b(val);
            } else if (mp < 8) {
                Kp[(((skv * NB + b) * NH + hh) * NSP + nrow) * HD + d] = f2b(val);
            } else {
                Vp[(((skv * NB + b) * NH + hh) * HD + d) * NSP + nrow] = f2b(val);
            }
        }
    }
}

// ---------------- Kernel 2: flash cross-attention (16x16x32 MFMA only) ----------------
// grid: (64 i-tiles of 64, 32 = s*16+b*4+h), 256 threads = 4 waves x 16 queries
__global__ __launch_bounds__(256) void k_attn(
    const unsigned short* __restrict__ Qp,
    const unsigned short* __restrict__ Kp,
    const unsigned short* __restrict__ Vp,
    unsigned short* __restrict__ Op)
{
    const int sbh = blockIdx.y;
    const int i0 = blockIdx.x * 64;
    const unsigned short* qb = Qp + sbh * (NSP * HD);
    const unsigned short* kb = Kp + sbh * (NSP * HD);
    const unsigned short* vb = Vp + sbh * (NSP * HD);
    const int t = threadIdx.x, lane = t & 63, w = t >> 6;
    const int q15 = lane & 15, g = lane >> 4;   // g in 0..3
    const int iw = i0 + 16 * w;

    const short8 zero8 = mk8(0u, 0u, 0u, 0u);

    // Q B-fragment: B[n=q15][k=8g+e] = Q[iw+q15][8g+e] for g<2, zero-padded k>=16.
    short8 qfv = (g < 2) ? *(const short8*)(qb + (iw + q15) * HD + g * 8) : zero8;

    f32x4 o, z4;
    o[0]=o[1]=o[2]=o[3]=0.f;
    z4[0]=z4[1]=z4[2]=z4[3]=0.f;
    float m = -1e30f, ssum = 0.f;

    __shared__ unsigned short kls[32 * 24];  // K tile [32 j][16 d]
    __shared__ unsigned short vls[16 * 40];  // V^T tile [16 d][32 j]

    for (int jt = 0; jt < 128; ++jt) {
        const int j0 = jt * 32;
        __syncthreads();
        if (t < 64) {
            const int j = t >> 1, dh = t & 1;
            *(u16x8*)&kls[j * 24 + dh * 8] = *(const u16x8*)(kb + (j0 + j) * HD + dh * 8);
        } else if (t < 128) {
            const int t2 = t - 64, d = t2 >> 2, jq = t2 & 3;
            *(u16x8*)&vls[d * 40 + jq * 8] = *(const u16x8*)(vb + d * NSP + j0 + jq * 8);
        }
        __syncthreads();

        // Two 16-j subtiles: st[tt][r] = S^T[j0+16*tt+4g+r][iw+q15]
        f32x4 st0, st1;
        {
            short8 kf0 = (g < 2) ? *(const short8*)&kls[q15 * 24 + g * 8] : zero8;
            short8 kf1 = (g < 2) ? *(const short8*)&kls[(16 + q15) * 24 + g * 8] : zero8;
            st0 = __builtin_amdgcn_mfma_f32_16x16x32_bf16(kf0, qfv, z4, 0, 0, 0);
            st1 = __builtin_amdgcn_mfma_f32_16x16x32_bf16(kf1, qfv, z4, 0, 0, 0);
        }

        // online softmax for query q15 (values spread over 4 g-groups)
        float tmax = fmaxf(fmaxf(fmaxf(st0[0], st0[1]), fmaxf(st0[2], st0[3])),
                           fmaxf(fmaxf(st1[0], st1[1]), fmaxf(st1[2], st1[3])));
        tmax = fmaxf(tmax, __shfl_xor(tmax, 16));
        tmax = fmaxf(tmax, __shfl_xor(tmax, 32));

        const float mnew = fmaxf(m, tmax);
        const float fac = exp2f(m - mnew);
        #pragma unroll
        for (int r = 0; r < 4; ++r) o[r] *= __shfl(fac, 4 * g + r);
        ssum *= fac;
        m = mnew;

        float p0[4], p1[4], pl = 0.f;
        #pragma unroll
        for (int r = 0; r < 4; ++r) {
            p0[r] = exp2f(st0[r] - m);
            p1[r] = exp2f(st1[r] - m);
            pl += p0[r] + p1[r];
        }
        pl += __shfl_xor(pl, 16);
        pl += __shfl_xor(pl, 32);
        ssum += pl;

        // Pack P into PV A-fragment: lane (q15,g) needs A[m=q15][k=8g+e] = P[q15][8g+e].
        // Owner of P[q][jj]: lane (q, ((jj&15)>>2)), subtile jj>>4, slot jj&3.
        unsigned w00 = cvtpk(p0[0], p0[1]), w01 = cvtpk(p0[2], p0[3]);
        unsigned w10 = cvtpk(p1[0], p1[1]), w11 = cvtpk(p1[2], p1[3]);
        const int s0 = ((g & 1) << 5) + q15;   // lane q + 16*(2*(g&1))
        const int s1 = s0 + 16;
        unsigned b00 = __shfl(w00, s0), b01 = __shfl(w01, s0);
        unsigned b10 = __shfl(w10, s0), b11 = __shfl(w11, s0);
        unsigned c00 = __shfl(w00, s1), c01 = __shfl(w01, s1);
        unsigned c10 = __shfl(w10, s1), c11 = __shfl(w11, s1);
        const int T = g >> 1;
        short8 pa = mk8(T ? b10 : b00, T ? b11 : b01, T ? c10 : c00, T ? c11 : c01);

        // V B-fragment: B[k=8g+e][n=d=q15] = V[j0+8g+e][d] from V^T LDS tile
        short8 vf = *(const short8*)&vls[q15 * 40 + g * 8];

        o = __builtin_amdgcn_mfma_f32_16x16x32_bf16(pa, vf, o, 0, 0, 0);
    }

    const float rinv = 1.0f / ssum;
    const int sb = sbh >> 2, h = sbh & 3;
    #pragma unroll
    for (int r = 0; r < 4; ++r) {
        const float rr = __shfl(rinv, 4 * g + r);   // query of o[r] is 4g+r
        const int irow = iw + 4 * g + r;
        Op[(sb * NSP + irow) * PROJD + h * HD + q15] = f2b(o[r] * rr);
    }
}

// ---------------- Kernel 3: out-projection + residual + group stats (fp32 out) ----------------
__global__ __launch_bounds__(256) void k_out(
    const unsigned short* __restrict__ feat_a, const unsigned short* __restrict__ feat_b,
    const unsigned short* __restrict__ prm,
    const unsigned short* __restrict__ Op,
    float* __restrict__ Y, float* __restrict__ stats)
{
    const int isf = detect_f32(feat_a);
    const int sb = blockIdx.y;
    const int s = sb >> 2, b = sb & 3;
    const int n0 = blockIdx.x * 16;
    const unsigned short* feat = s ? feat_b : feat_a;
    const unsigned short* OW = prm + (s ? 14 : 12) * SL;
    const unsigned short* OB = prm + (s ? 15 : 13) * SL;
    const int t = threadIdx.x, lane = t & 63, w = t >> 6;
    const unsigned short* ob = Op + sb * (NSP * PROJD);

    f32x4 acc[4];
    #pragma unroll
    for (int i = 0; i < 4; ++i)
        #pragma unroll
        for (int r = 0; r < 4; ++r) acc[i][r] = 0.f;

    #pragma unroll
    for (int kc = 0; kc < PROJD; kc += 32) {
        short8 bf = *(const short8*)(ob + (n0 + (lane & 15)) * PROJD + kc + (lane >> 4) * 8);
        #pragma unroll
        for (int mc = 0; mc < 4; ++mc) {
            const int c = 64 * w + mc * 16 + (lane & 15);
            short8 af = *(const short8*)(OW + c * PROJD + kc + (lane >> 4) * 8);
            acc[mc] = __builtin_amdgcn_mfma_f32_16x16x32_bf16(af, bf, acc[mc], 0, 0, 0);
        }
    }

    const int ncol = n0 + (lane & 15);
    #pragma unroll
    for (int mc = 0; mc < 4; ++mc) {
        float gs = 0.f, gq = 0.f;
        #pragma unroll
        for (int r = 0; r < 4; ++r) {
            const int c = 64 * w + mc * 16 + (lane >> 4) * 4 + r;
            const size_t fidx = (size_t)(b * CHN + c) * NSP + ncol;
            const float fv = isf ? ((const float*)feat)[fidx] : b2f(feat[fidx]);
            const float val = acc[mc][r] + b2f(OB[c]) + fv;
            Y[(sb * CHN + c) * NSP + ncol] = val;
            gs += val; gq += val * val;
        }
        #pragma unroll
        for (int off = 1; off < 64; off <<= 1) {
            gs += __shfl_xor(gs, off);
            gq += __shfl_xor(gq, off);
        }
        if (lane == 0) {
            atomicAdd(&stats[(sb * 16 + 4 * w + mc) * 2], gs);
            atomicAdd(&stats[(sb * 16 + 4 * w + mc) * 2 + 1], gq);
        }
    }
}

// ---------------- Kernel 4: group norm apply (in-place, fp32 d_out) ----------------
__global__ __launch_bounds__(256) void k_norm(
    float* __restrict__ out, const float* __restrict__ stats,
    const unsigned short* __restrict__ prm)
{
    const int e0 = (blockIdx.x * 256 + threadIdx.x) * 8;
    const int c = (e0 >> 12) & 255;
    const int sb = e0 >> 20;
    const int s = sb >> 2;
    const int g = c >> 4;
    const float s1 = stats[(sb * 16 + g) * 2];
    const float s2 = stats[(sb * 16 + g) * 2 + 1];
    const float inv = 1.0f / 65536.0f;
    const float mean = s1 * inv;
    const float var = s2 * inv - mean * mean;
    const float rstd = rsqrtf(var + 1e-5f);
    const float gamma = b2f(prm[(s ? 18 : 16) * SL + c]);
    const float beta  = b2f(prm[(s ? 19 : 17) * SL + c]);
    const float a = rstd * gamma;
    const float bb = beta - mean * a;
    f32x4 y0 = *(const f32x4*)(out + e0);
    f32x4 y1 = *(const f32x4*)(out + e0 + 4);
    #pragma unroll
    for (int e = 0; e < 4; ++e) { y0[e] = y0[e] * a + bb; y1[e] = y1[e] * a + bb; }
    *(f32x4*)(out + e0) = y0;
    *(f32x4*)(out + e0 + 4) = y1;
}

extern "C" void kernel_launch(void* const* d_in, const int* in_sizes, int n_in,
                              void* d_out, int out_size, void* d_ws, size_t ws_size,
                              hipStream_t stream)
{
    const unsigned short* feat_a = (const unsigned short*)d_in[0];
    const unsigned short* feat_b = (const unsigned short*)d_in[1];

    char* ws = (char*)d_ws;
    unsigned short* Qp = (unsigned short*)(ws);
    unsigned short* Kp = (unsigned short*)(ws + (4u << 20));
    unsigned short* Vp = (unsigned short*)(ws + (8u << 20));
    unsigned short* Op = (unsigned short*)(ws + (12u << 20));
    float* stats = (float*)(ws + (16u << 20));
    unsigned short* prm = (unsigned short*)(ws + (16u << 20) + 65536);

    P20 ptrs;
    for (int i = 0; i < 20; ++i) ptrs.p[i] = d_in[2 + i];

    float* out = (float*)d_out;

    hipMemsetAsync(stats, 0, 256 * sizeof(float), stream);
    k_conv<<<20, 256, 0, stream>>>(ptrs, feat_a, prm);
    k_proj<<<dim3(64, 8), 256, 0, stream>>>(feat_a, feat_b, prm, Qp, Kp, Vp);
    k_attn<<<dim3(64, 32), 256, 0, stream>>>(Qp, Kp, Vp, Op);
    k_out<<<dim3(256, 8), 256, 0, stream>>>(feat_a, feat_b, prm, Op, out, stats);
    k_norm<<<4096, 256, 0, stream>>>(out, stats, prm);
}

// Round 7
// 523.471 us; speedup vs baseline: 1.1446x; 1.1446x over previous
//
#include <hip/hip_runtime.h>

typedef __attribute__((ext_vector_type(8))) short short8;
typedef __attribute__((ext_vector_type(8))) unsigned short u16x8;
typedef __attribute__((ext_vector_type(4))) unsigned short u16x4;
typedef __attribute__((ext_vector_type(4))) float f32x4;
typedef __attribute__((ext_vector_type(16))) float f32x16;

#define NB 4
#define CHN 256
#define NSP 4096
#define PROJD 64
#define NH 4
#define HD 16
#define SL 16384
#define QSCALE 0.36067376022224085f  // SCALE(0.25) * log2(e)

__device__ __forceinline__ float b2f(unsigned short u) {
    union { unsigned ui; float f; } x; x.ui = ((unsigned)u) << 16; return x.f;
}
__device__ __forceinline__ unsigned short f2b(float f) {
    union { float f; unsigned ui; } x; x.f = f;
    unsigned r = x.ui + 0x7fffu + ((x.ui >> 16) & 1u);
    return (unsigned short)(r >> 16);
}
__device__ __forceinline__ unsigned cvtpk(float lo, float hi) {
    unsigned r;
    asm("v_cvt_pk_bf16_f32 %0, %1, %2" : "=v"(r) : "v"(lo), "v"(hi));
    return r;
}
__device__ __forceinline__ void plswap(unsigned &a, unsigned &b) {
    asm volatile("v_permlane32_swap_b32 %0, %1" : "+v"(a), "+v"(b));
}
__device__ __forceinline__ short8 mk8(unsigned a, unsigned b, unsigned c, unsigned d) {
    union { unsigned u[4]; short8 v; } x;
    x.u[0] = a; x.u[1] = b; x.u[2] = c; x.u[3] = d;
    return x.v;
}

// Detect underlying dtype of feat buffer: returns 1 if fp32, 0 if bf16.
__device__ __forceinline__ int detect_f32(const unsigned short* fa) {
    const int t = threadIdx.x;
    __shared__ int sflag;
    if (t < 64) {
        int wild = 0;
        #pragma unroll
        for (int e = 0; e < 8; ++e) {
            unsigned short u = fa[(t * 8 + e) * 2];
            int ex = (u >> 7) & 0xFF;
            if (ex != 0 && (ex < 0x6E || ex > 0x8A)) wild++;
        }
        #pragma unroll
        for (int off = 1; off < 64; off <<= 1) wild += __shfl_xor(wild, off);
        if (t == 0) sflag = (wild > 64) ? 1 : 0;
    }
    __syncthreads();
    return sflag;
}

struct P20 { const void* p[20]; };

// ---------------- Kernel 0: canonicalize the 20 param tensors to bf16 slots ----------------
__global__ __launch_bounds__(256) void k_conv(P20 ptrs, const unsigned short* feat_a,
                                              unsigned short* dst) {
    const int isf = detect_f32(feat_a);
    const int id = blockIdx.x;
    const int sizes[20] = {16384,64,16384,64,16384,64,16384,64,16384,64,16384,64,
                           16384,256,16384,256,256,256,256,256};
    const int n = sizes[id];
    unsigned short* o = dst + id * SL;
    if (isf) {
        const float* s = (const float*)ptrs.p[id];
        for (int i = threadIdx.x; i < n; i += 256) o[i] = f2b(s[i]);
    } else {
        const unsigned short* s = (const unsigned short*)ptrs.p[id];
        for (int i = threadIdx.x; i < n; i += 256) o[i] = s[i];
    }
}

// ---------------- Kernel 1: QKV projections ----------------
__global__ __launch_bounds__(256) void k_proj(
    const unsigned short* __restrict__ feat_a, const unsigned short* __restrict__ feat_b,
    const unsigned short* __restrict__ prm,
    unsigned short* __restrict__ Qp, unsigned short* __restrict__ Kp,
    unsigned short* __restrict__ Vp)
{
    const int isf = detect_f32(feat_a);
    const int f = blockIdx.y >> 2;
    const int b = blockIdx.y & 3;
    const int n0 = blockIdx.x * 64;
    const unsigned short* feat = f ? feat_b : feat_a;
    const unsigned short* wq  = prm + (f ? 6 : 0) * SL;
    const unsigned short* biq = prm + (f ? 7 : 1) * SL;
    const unsigned short* wk  = prm + (f ? 2 : 8) * SL;
    const unsigned short* bik = prm + (f ? 3 : 9) * SL;
    const unsigned short* wv  = prm + (f ? 4 : 10) * SL;
    const unsigned short* biv = prm + (f ? 5 : 11) * SL;
    const int sq = f, skv = 1 - f;

    __shared__ unsigned short lds[64 * 40];   // feat^T tile [64 n][32 c], row stride 40 shorts
    const int t = threadIdx.x;
    const int lane = t & 63, w = t >> 6;

    f32x4 acc[12];
    #pragma unroll
    for (int i = 0; i < 12; ++i)
        #pragma unroll
        for (int r = 0; r < 4; ++r) acc[i][r] = 0.f;

    for (int c0 = 0; c0 < CHN; c0 += 32) {
        __syncthreads();
        {
            const int cc = t >> 3, nn = (t & 7) * 8;
            const size_t base = (size_t)(b * CHN + c0 + cc) * NSP + n0 + nn;
            if (isf) {
                const float* ff = (const float*)feat;
                f32x4 v0 = *(const f32x4*)(ff + base);
                f32x4 v1 = *(const f32x4*)(ff + base + 4);
                #pragma unroll
                for (int e = 0; e < 4; ++e) {
                    lds[(nn + e) * 40 + cc] = f2b(v0[e]);
                    lds[(nn + 4 + e) * 40 + cc] = f2b(v1[e]);
                }
            } else {
                u16x8 v = *(const u16x8*)(feat + base);
                #pragma unroll
                for (int e = 0; e < 8; ++e) lds[(nn + e) * 40 + cc] = v[e];
            }
        }
        __syncthreads();
        short8 af = *(const short8*)&lds[(16 * w + (lane & 15)) * 40 + (lane >> 4) * 8];
        #pragma unroll
        for (int mp = 0; mp < 12; ++mp) {
            const unsigned short* W = mp < 4 ? wq : (mp < 8 ? wk : wv);
            const int prow = (mp & 3) * 16 + (lane & 15);
            short8 bf = *(const short8*)(W + prow * CHN + c0 + (lane >> 4) * 8);
            acc[mp] = __builtin_amdgcn_mfma_f32_16x16x32_bf16(af, bf, acc[mp], 0, 0, 0);
        }
    }

    #pragma unroll
    for (int mp = 0; mp < 12; ++mp) {
        const unsigned short* Bi = mp < 4 ? biq : (mp < 8 ? bik : biv);
        const int hh = mp & 3, d = lane & 15;
        const float bias = b2f(Bi[hh * 16 + d]);
        if (mp < 8) {
            #pragma unroll
            for (int r = 0; r < 4; ++r) {
                const int nrow = n0 + 16 * w + (lane >> 4) * 4 + r;
                float val = acc[mp][r] + bias;
                if (mp < 4) {
                    val *= QSCALE;
                    Qp[(((sq * NB + b) * NH + hh) * NSP + nrow) * HD + d] = f2b(val);
                } else {
                    Kp[(((skv * NB + b) * NH + hh) * NSP + nrow) * HD + d] = f2b(val);
                }
            }
        } else {
            // V^T (d-major) write: 4 consecutive n per lane -> one 8B store
            const int nrow0 = n0 + 16 * w + (lane >> 4) * 4;
            u16x4 pk;
            #pragma unroll
            for (int r = 0; r < 4; ++r) pk[r] = f2b(acc[mp][r] + bias);
            *(u16x4*)(Vp + ((size_t)((skv * NB + b) * NH + hh) * HD + d) * NSP + nrow0) = pk;
        }
    }
}

// ---------------- Kernel 2: flash cross-attention (32x32x16, LDS-free, barrier-free) ----------------
// grid: (32 i-tiles of 128, 32 = s*16+b*4+h), 256 threads = 4 waves x 32 queries
__global__ __launch_bounds__(256) void k_attn(
    const unsigned short* __restrict__ Qp,
    const unsigned short* __restrict__ Kp,
    const unsigned short* __restrict__ Vp,
    unsigned short* __restrict__ Op)
{
    const int sbh = blockIdx.y;
    const int i0 = blockIdx.x * 128;
    const unsigned short* qb = Qp + sbh * (NSP * HD);
    const unsigned short* kb = Kp + sbh * (NSP * HD);
    const unsigned short* vb = Vp + sbh * (NSP * HD);
    const int t = threadIdx.x, lane = t & 63, w = t >> 6;
    const int lo5 = lane & 31, hi = lane >> 5;
    const int iw = i0 + 32 * w;
    const int dd = lo5 & 15;

    // Q B-fragment: B[k=d][n=q=lo5], k = 8*hi+e
    short8 qf = *(const short8*)(qb + (iw + lo5) * HD + hi * 8);
    const unsigned short* vrow = vb + (size_t)dd * NSP;

    f32x16 o, z16;
    #pragma unroll
    for (int r = 0; r < 16; ++r) { o[r] = 0.f; z16[r] = 0.f; }
    float m = -1e30f, ssum = 0.f;

    #pragma unroll 2
    for (int jt = 0; jt < 128; ++jt) {
        const int j0 = jt * 32;
        // K A-fragment straight from global (L2-resident): A[m=j=lo5][k=d=8hi+e]
        short8 kf = *(const short8*)(kb + (j0 + lo5) * HD + hi * 8);
        // V B-fragments: B[k=j][n=d=dd], k = 16t + 8hi + e
        short8 vf0 = *(const short8*)(vrow + j0 + hi * 8);
        short8 vf1 = *(const short8*)(vrow + j0 + 16 + hi * 8);

        f32x16 st = __builtin_amdgcn_mfma_f32_32x32x16_bf16(kf, qf, z16, 0, 0, 0);

        float t0 = fmaxf(fmaxf(st[0], st[1]),  fmaxf(st[2], st[3]));
        float t1 = fmaxf(fmaxf(st[4], st[5]),  fmaxf(st[6], st[7]));
        float t2 = fmaxf(fmaxf(st[8], st[9]),  fmaxf(st[10], st[11]));
        float t3 = fmaxf(fmaxf(st[12], st[13]), fmaxf(st[14], st[15]));
        float tmax = fmaxf(fmaxf(t0, t1), fmaxf(t2, t3));
        tmax = fmaxf(tmax, __shfl_xor(tmax, 32));

        if (__any(tmax > m + 8.f)) {       // defer-max rescale (rare)
            const float mnew = fmaxf(m, tmax);
            const float fac = exp2f(m - mnew);
            #pragma unroll
            for (int r = 0; r < 16; ++r) {
                const float fr = __shfl(fac, (r & 3) + 8 * (r >> 2) + 4 * hi);
                o[r] *= fr;
            }
            ssum *= fac;
            m = mnew;
        }

        float p[16], pl = 0.f;
        #pragma unroll
        for (int r = 0; r < 16; ++r) { p[r] = exp2f(st[r] - m); pl += p[r]; }
        ssum += pl + __shfl_xor(pl, 32);

        // pack P (S^T C/D layout) into PV A-fragments via cvt_pk + permlane32_swap
        unsigned w0 = cvtpk(p[0], p[1]),  w1 = cvtpk(p[2], p[3]);
        unsigned w2 = cvtpk(p[4], p[5]),  w3 = cvtpk(p[6], p[7]);
        plswap(w0, w2); plswap(w1, w3);
        unsigned w4 = cvtpk(p[8], p[9]),  w5 = cvtpk(p[10], p[11]);
        unsigned w6 = cvtpk(p[12], p[13]), w7 = cvtpk(p[14], p[15]);
        plswap(w4, w6); plswap(w5, w7);
        short8 pa0 = mk8(w0, w1, w2, w3);
        short8 pa1 = mk8(w4, w5, w6, w7);

        o = __builtin_amdgcn_mfma_f32_32x32x16_bf16(pa0, vf0, o, 0, 0, 0);
        o = __builtin_amdgcn_mfma_f32_32x32x16_bf16(pa1, vf1, o, 0, 0, 0);
    }

    const float rinv = 1.0f / ssum;
    float rr[16];
    #pragma unroll
    for (int r = 0; r < 16; ++r) rr[r] = __shfl(rinv, (r & 3) + 8 * (r >> 2) + 4 * hi);

    const int sb = sbh >> 2, h = sbh & 3;
    if (lo5 < 16) {
        #pragma unroll
        for (int r = 0; r < 16; ++r) {
            const int irow = iw + (r & 3) + 8 * (r >> 2) + 4 * hi;
            Op[(sb * NSP + irow) * PROJD + h * HD + dd] = f2b(o[r] * rr[r]);
        }
    }
}

// ---------------- Kernel 3: out-projection + residual + group stats (fp32 out) ----------------
__global__ __launch_bounds__(256) void k_out(
    const unsigned short* __restrict__ feat_a, const unsigned short* __restrict__ feat_b,
    const unsigned short* __restrict__ prm,
    const unsigned short* __restrict__ Op,
    float* __restrict__ Y, float* __restrict__ stats)
{
    const int isf = detect_f32(feat_a);
    const int sb = blockIdx.y;
    const int s = sb >> 2, b = sb & 3;
    const int n0 = blockIdx.x * 16;
    const unsigned short* feat = s ? feat_b : feat_a;
    const unsigned short* OW = prm + (s ? 14 : 12) * SL;
    const unsigned short* OB = prm + (s ? 15 : 13) * SL;
    const int t = threadIdx.x, lane = t & 63, w = t >> 6;
    const unsigned short* ob = Op + sb * (NSP * PROJD);

    f32x4 acc[4];
    #pragma unroll
    for (int i = 0; i < 4; ++i)
        #pragma unroll
        for (int r = 0; r < 4; ++r) acc[i][r] = 0.f;

    #pragma unroll
    for (int kc = 0; kc < PROJD; kc += 32) {
        short8 bf = *(const short8*)(ob + (n0 + (lane & 15)) * PROJD + kc + (lane >> 4) * 8);
        #pragma unroll
        for (int mc = 0; mc < 4; ++mc) {
            const int c = 64 * w + mc * 16 + (lane & 15);
            short8 af = *(const short8*)(OW + c * PROJD + kc + (lane >> 4) * 8);
            acc[mc] = __builtin_amdgcn_mfma_f32_16x16x32_bf16(af, bf, acc[mc], 0, 0, 0);
        }
    }

    const int ncol = n0 + (lane & 15);
    #pragma unroll
    for (int mc = 0; mc < 4; ++mc) {
        float gs = 0.f, gq = 0.f;
        #pragma unroll
        for (int r = 0; r < 4; ++r) {
            const int c = 64 * w + mc * 16 + (lane >> 4) * 4 + r;
            const size_t fidx = (size_t)(b * CHN + c) * NSP + ncol;
            const float fv = isf ? ((const float*)feat)[fidx] : b2f(feat[fidx]);
            const float val = acc[mc][r] + b2f(OB[c]) + fv;
            Y[(sb * CHN + c) * NSP + ncol] = val;
            gs += val; gq += val * val;
        }
        #pragma unroll
        for (int off = 1; off < 64; off <<= 1) {
            gs += __shfl_xor(gs, off);
            gq += __shfl_xor(gq, off);
        }
        if (lane == 0) {
            atomicAdd(&stats[(sb * 16 + 4 * w + mc) * 2], gs);
            atomicAdd(&stats[(sb * 16 + 4 * w + mc) * 2 + 1], gq);
        }
    }
}

// ---------------- Kernel 4: group norm apply (in-place, fp32 d_out) ----------------
__global__ __launch_bounds__(256) void k_norm(
    float* __restrict__ out, const float* __restrict__ stats,
    const unsigned short* __restrict__ prm)
{
    const int e0 = (blockIdx.x * 256 + threadIdx.x) * 8;
    const int c = (e0 >> 12) & 255;
    const int sb = e0 >> 20;
    const int s = sb >> 2;
    const int g = c >> 4;
    const float s1 = stats[(sb * 16 + g) * 2];
    const float s2 = stats[(sb * 16 + g) * 2 + 1];
    const float inv = 1.0f / 65536.0f;
    const float mean = s1 * inv;
    const float var = s2 * inv - mean * mean;
    const float rstd = rsqrtf(var + 1e-5f);
    const float gamma = b2f(prm[(s ? 18 : 16) * SL + c]);
    const float beta  = b2f(prm[(s ? 19 : 17) * SL + c]);
    const float a = rstd * gamma;
    const float bb = beta - mean * a;
    f32x4 y0 = *(const f32x4*)(out + e0);
    f32x4 y1 = *(const f32x4*)(out + e0 + 4);
    #pragma unroll
    for (int e = 0; e < 4; ++e) { y0[e] = y0[e] * a + bb; y1[e] = y1[e] * a + bb; }
    *(f32x4*)(out + e0) = y0;
    *(f32x4*)(out + e0 + 4) = y1;
}

extern "C" void kernel_launch(void* const* d_in, const int* in_sizes, int n_in,
                              void* d_out, int out_size, void* d_ws, size_t ws_size,
                              hipStream_t stream)
{
    const unsigned short* feat_a = (const unsigned short*)d_in[0];
    const unsigned short* feat_b = (const unsigned short*)d_in[1];

    char* ws = (char*)d_ws;
    unsigned short* Qp = (unsigned short*)(ws);
    unsigned short* Kp = (unsigned short*)(ws + (4u << 20));
    unsigned short* Vp = (unsigned short*)(ws + (8u << 20));
    unsigned short* Op = (unsigned short*)(ws + (12u << 20));
    float* stats = (float*)(ws + (16u << 20));
    unsigned short* prm = (unsigned short*)(ws + (16u << 20) + 65536);

    P20 ptrs;
    for (int i = 0; i < 20; ++i) ptrs.p[i] = d_in[2 + i];

    float* out = (float*)d_out;

    hipMemsetAsync(stats, 0, 256 * sizeof(float), stream);
    k_conv<<<20, 256, 0, stream>>>(ptrs, feat_a, prm);
    k_proj<<<dim3(64, 8), 256, 0, stream>>>(feat_a, feat_b, prm, Qp, Kp, Vp);
    k_attn<<<dim3(32, 32), 256, 0, stream>>>(Qp, Kp, Vp, Op);
    k_out<<<dim3(256, 8), 256, 0, stream>>>(feat_a, feat_b, prm, Op, out, stats);
    k_norm<<<4096, 256, 0, stream>>>(out, stats, prm);
}

// Round 8
// 371.798 us; speedup vs baseline: 1.6115x; 1.4079x over previous
//
#include <hip/hip_runtime.h>

typedef __attribute__((ext_vector_type(8))) short short8;
typedef __attribute__((ext_vector_type(8))) unsigned short u16x8;
typedef __attribute__((ext_vector_type(4))) unsigned short u16x4;
typedef __attribute__((ext_vector_type(4))) float f32x4;
typedef __attribute__((ext_vector_type(16))) float f32x16;

#define NB 4
#define CHN 256
#define NSP 4096
#define PROJD 64
#define NH 4
#define HD 16
#define SL 16384
#define QSCALE 0.36067376022224085f  // SCALE(0.25) * log2(e)
#define FMAX 16.0f                   // fixed softmax max (log2 domain)

__device__ __forceinline__ float b2f(unsigned short u) {
    union { unsigned ui; float f; } x; x.ui = ((unsigned)u) << 16; return x.f;
}
__device__ __forceinline__ unsigned short f2b(float f) {
    union { float f; unsigned ui; } x; x.f = f;
    unsigned r = x.ui + 0x7fffu + ((x.ui >> 16) & 1u);
    return (unsigned short)(r >> 16);
}
__device__ __forceinline__ unsigned cvtpk(float lo, float hi) {
    unsigned r;
    asm("v_cvt_pk_bf16_f32 %0, %1, %2" : "=v"(r) : "v"(lo), "v"(hi));
    return r;
}
__device__ __forceinline__ void plswap(unsigned &a, unsigned &b) {
    asm volatile("v_permlane32_swap_b32 %0, %1" : "+v"(a), "+v"(b));
}
__device__ __forceinline__ short8 mk8(unsigned a, unsigned b, unsigned c, unsigned d) {
    union { unsigned u[4]; short8 v; } x;
    x.u[0] = a; x.u[1] = b; x.u[2] = c; x.u[3] = d;
    return x.v;
}

// Detect underlying dtype of feat buffer: returns 1 if fp32, 0 if bf16.
__device__ __forceinline__ int detect_f32(const unsigned short* fa) {
    const int t = threadIdx.x;
    __shared__ int sflag;
    if (t < 64) {
        int wild = 0;
        #pragma unroll
        for (int e = 0; e < 8; ++e) {
            unsigned short u = fa[(t * 8 + e) * 2];
            int ex = (u >> 7) & 0xFF;
            if (ex != 0 && (ex < 0x6E || ex > 0x8A)) wild++;
        }
        #pragma unroll
        for (int off = 1; off < 64; off <<= 1) wild += __shfl_xor(wild, off);
        if (t == 0) sflag = (wild > 64) ? 1 : 0;
    }
    __syncthreads();
    return sflag;
}

struct P20 { const void* p[20]; };

// ---------------- Kernel 0: canonicalize the 20 param tensors to bf16 slots ----------------
__global__ __launch_bounds__(256) void k_conv(P20 ptrs, const unsigned short* feat_a,
                                              unsigned short* dst) {
    const int isf = detect_f32(feat_a);
    const int id = blockIdx.x;
    const int sizes[20] = {16384,64,16384,64,16384,64,16384,64,16384,64,16384,64,
                           16384,256,16384,256,256,256,256,256};
    const int n = sizes[id];
    unsigned short* o = dst + id * SL;
    if (isf) {
        const float* s = (const float*)ptrs.p[id];
        for (int i = threadIdx.x; i < n; i += 256) o[i] = f2b(s[i]);
    } else {
        const unsigned short* s = (const unsigned short*)ptrs.p[id];
        for (int i = threadIdx.x; i < n; i += 256) o[i] = s[i];
    }
}

// ---------------- Kernel 1: QKV projections ----------------
__global__ __launch_bounds__(256) void k_proj(
    const unsigned short* __restrict__ feat_a, const unsigned short* __restrict__ feat_b,
    const unsigned short* __restrict__ prm,
    unsigned short* __restrict__ Qp, unsigned short* __restrict__ Kp,
    unsigned short* __restrict__ Vp)
{
    const int isf = detect_f32(feat_a);
    const int f = blockIdx.y >> 2;
    const int b = blockIdx.y & 3;
    const int n0 = blockIdx.x * 64;
    const unsigned short* feat = f ? feat_b : feat_a;
    const unsigned short* wq  = prm + (f ? 6 : 0) * SL;
    const unsigned short* biq = prm + (f ? 7 : 1) * SL;
    const unsigned short* wk  = prm + (f ? 2 : 8) * SL;
    const unsigned short* bik = prm + (f ? 3 : 9) * SL;
    const unsigned short* wv  = prm + (f ? 4 : 10) * SL;
    const unsigned short* biv = prm + (f ? 5 : 11) * SL;
    const int sq = f, skv = 1 - f;

    __shared__ unsigned short lds[64 * 40];   // feat^T tile [64 n][32 c], row stride 40 shorts
    const int t = threadIdx.x;
    const int lane = t & 63, w = t >> 6;

    f32x4 acc[12];
    #pragma unroll
    for (int i = 0; i < 12; ++i)
        #pragma unroll
        for (int r = 0; r < 4; ++r) acc[i][r] = 0.f;

    for (int c0 = 0; c0 < CHN; c0 += 32) {
        __syncthreads();
        {
            const int cc = t >> 3, nn = (t & 7) * 8;
            const size_t base = (size_t)(b * CHN + c0 + cc) * NSP + n0 + nn;
            if (isf) {
                const float* ff = (const float*)feat;
                f32x4 v0 = *(const f32x4*)(ff + base);
                f32x4 v1 = *(const f32x4*)(ff + base + 4);
                #pragma unroll
                for (int e = 0; e < 4; ++e) {
                    lds[(nn + e) * 40 + cc] = f2b(v0[e]);
                    lds[(nn + 4 + e) * 40 + cc] = f2b(v1[e]);
                }
            } else {
                u16x8 v = *(const u16x8*)(feat + base);
                #pragma unroll
                for (int e = 0; e < 8; ++e) lds[(nn + e) * 40 + cc] = v[e];
            }
        }
        __syncthreads();
        short8 af = *(const short8*)&lds[(16 * w + (lane & 15)) * 40 + (lane >> 4) * 8];
        #pragma unroll
        for (int mp = 0; mp < 12; ++mp) {
            const unsigned short* W = mp < 4 ? wq : (mp < 8 ? wk : wv);
            const int prow = (mp & 3) * 16 + (lane & 15);
            short8 bf = *(const short8*)(W + prow * CHN + c0 + (lane >> 4) * 8);
            acc[mp] = __builtin_amdgcn_mfma_f32_16x16x32_bf16(af, bf, acc[mp], 0, 0, 0);
        }
    }

    #pragma unroll
    for (int mp = 0; mp < 12; ++mp) {
        const unsigned short* Bi = mp < 4 ? biq : (mp < 8 ? bik : biv);
        const int hh = mp & 3, d = lane & 15;
        const float bias = b2f(Bi[hh * 16 + d]);
        if (mp < 8) {
            #pragma unroll
            for (int r = 0; r < 4; ++r) {
                const int nrow = n0 + 16 * w + (lane >> 4) * 4 + r;
                float val = acc[mp][r] + bias;
                if (mp < 4) {
                    val *= QSCALE;
                    Qp[(((sq * NB + b) * NH + hh) * NSP + nrow) * HD + d] = f2b(val);
                } else {
                    Kp[(((skv * NB + b) * NH + hh) * NSP + nrow) * HD + d] = f2b(val);
                }
            }
        } else {
            // V^T (d-major) write: 4 consecutive n per lane -> one 8B store
            const int nrow0 = n0 + 16 * w + (lane >> 4) * 4;
            u16x4 pk;
            #pragma unroll
            for (int r = 0; r < 4; ++r) pk[r] = f2b(acc[mp][r] + bias);
            *(u16x4*)(Vp + ((size_t)((skv * NB + b) * NH + hh) * HD + d) * NSP + nrow0) = pk;
        }
    }
}

// ---------------- Kernel 2: flash cross-attention ----------------
// Fixed-max softmax (m=16, folded into QK^T C-operand), denominator via
// all-ones PV column (n=16). grid: (64 i-tiles of 64, 32 sbh), 128 thr = 2 waves.
__global__ __launch_bounds__(128) void k_attn(
    const unsigned short* __restrict__ Qp,
    const unsigned short* __restrict__ Kp,
    const unsigned short* __restrict__ Vp,
    unsigned short* __restrict__ Op)
{
    const int sbh = blockIdx.y;
    const int i0 = blockIdx.x * 64;
    const unsigned short* qb = Qp + sbh * (NSP * HD);
    const unsigned short* kb = Kp + sbh * (NSP * HD);
    const unsigned short* vb = Vp + sbh * (NSP * HD);
    const int t = threadIdx.x, lane = t & 63, w = t >> 6;
    const int lo5 = lane & 31, hi = lane >> 5;
    const int iw = i0 + 32 * w;
    const int dd = lo5 & 15;

    // Q B-fragment: B[k=d=8hi+e][n=q=lo5]
    short8 qf = *(const short8*)(qb + (iw + lo5) * HD + hi * 8);
    const unsigned short* vrow = vb + (size_t)dd * NSP;
    const bool vload = lo5 < 16;
    const unsigned one2 = 0x3f803f80u;   // bf16 1.0 pair
    const short8 vcst = (lo5 == 16) ? mk8(one2, one2, one2, one2) : mk8(0u, 0u, 0u, 0u);

    f32x16 o, cinit;
    #pragma unroll
    for (int r = 0; r < 16; ++r) { o[r] = 0.f; cinit[r] = -FMAX; }

    #pragma unroll 2
    for (int jt = 0; jt < 128; ++jt) {
        const int j0 = jt * 32;
        // K A-fragment from global (L2-resident): A[m=j=lo5][k=d=8hi+e]
        short8 kf = *(const short8*)(kb + (j0 + lo5) * HD + hi * 8);
        // V B-fragments: B[k=j][n=dd] for lo5<16; ones column at n=16
        short8 vf0 = vcst, vf1 = vcst;
        if (vload) {
            vf0 = *(const short8*)(vrow + j0 + hi * 8);
            vf1 = *(const short8*)(vrow + j0 + 16 + hi * 8);
        }

        // st = K·Q - FMAX (fixed max folded into C-in)
        f32x16 st = __builtin_amdgcn_mfma_f32_32x32x16_bf16(kf, qf, cinit, 0, 0, 0);

        float p[16];
        #pragma unroll
        for (int r = 0; r < 16; ++r) p[r] = exp2f(st[r]);

        // pack P (S^T C/D layout) into PV A-fragments via cvt_pk + permlane32_swap
        unsigned w0 = cvtpk(p[0], p[1]),  w1 = cvtpk(p[2], p[3]);
        unsigned w2 = cvtpk(p[4], p[5]),  w3 = cvtpk(p[6], p[7]);
        plswap(w0, w2); plswap(w1, w3);
        unsigned w4 = cvtpk(p[8], p[9]),  w5 = cvtpk(p[10], p[11]);
        unsigned w6 = cvtpk(p[12], p[13]), w7 = cvtpk(p[14], p[15]);
        plswap(w4, w6); plswap(w5, w7);
        short8 pa0 = mk8(w0, w1, w2, w3);
        short8 pa1 = mk8(w4, w5, w6, w7);

        o = __builtin_amdgcn_mfma_f32_32x32x16_bf16(pa0, vf0, o, 0, 0, 0);
        o = __builtin_amdgcn_mfma_f32_32x32x16_bf16(pa1, vf1, o, 0, 0, 0);
    }

    // denominator for query row crow(r,hi) sits in lane (hi*32+16), reg r
    float rr[16];
    #pragma unroll
    for (int r = 0; r < 16; ++r) rr[r] = __shfl(o[r], (hi << 5) + 16);

    const int sb = sbh >> 2, h = sbh & 3;
    if (lo5 < 16) {
        #pragma unroll
        for (int r = 0; r < 16; ++r) {
            const int irow = iw + (r & 3) + 8 * (r >> 2) + 4 * hi;
            Op[(sb * NSP + irow) * PROJD + h * HD + dd] = f2b(o[r] / rr[r]);
        }
    }
}

// ---------------- Kernel 3: out-projection + residual + group stats (fp32 out) ----------------
// A = Op tile (m = spatial n), B = OW (n-dim = channel c) -> rows are 4
// consecutive n per lane: f32x4 residual loads + f32x4 Y stores.
// grid: (64 n-tiles of 64, 8 sb), 256 threads = 4 waves (wave w: 64 channels)
__global__ __launch_bounds__(256) void k_out(
    const unsigned short* __restrict__ feat_a, const unsigned short* __restrict__ feat_b,
    const unsigned short* __restrict__ prm,
    const unsigned short* __restrict__ Op,
    float* __restrict__ Y, float* __restrict__ stats)
{
    const int isf = detect_f32(feat_a);
    const int sb = blockIdx.y;
    const int s = sb >> 2, b = sb & 3;
    const int n0 = blockIdx.x * 64;
    const unsigned short* feat = s ? feat_b : feat_a;
    const unsigned short* OW = prm + (s ? 14 : 12) * SL;
    const unsigned short* OB = prm + (s ? 15 : 13) * SL;
    const int t = threadIdx.x, lane = t & 63, w = t >> 6;
    const unsigned short* ob = Op + (size_t)sb * (NSP * PROJD);
    const int l15 = lane & 15, lh = lane >> 4;

    f32x4 acc[4][4];   // [mn][mc]
    #pragma unroll
    for (int i = 0; i < 4; ++i)
        #pragma unroll
        for (int j = 0; j < 4; ++j)
            #pragma unroll
            for (int r = 0; r < 4; ++r) acc[i][j][r] = 0.f;

    #pragma unroll
    for (int kc = 0; kc < PROJD; kc += 32) {
        short8 af[4], bf[4];
        #pragma unroll
        for (int mn = 0; mn < 4; ++mn)
            af[mn] = *(const short8*)(ob + (n0 + mn * 16 + l15) * PROJD + kc + lh * 8);
        #pragma unroll
        for (int mc = 0; mc < 4; ++mc)
            bf[mc] = *(const short8*)(OW + (64 * w + mc * 16 + l15) * PROJD + kc + lh * 8);
        #pragma unroll
        for (int mn = 0; mn < 4; ++mn)
            #pragma unroll
            for (int mc = 0; mc < 4; ++mc)
                acc[mn][mc] = __builtin_amdgcn_mfma_f32_16x16x32_bf16(af[mn], bf[mc], acc[mn][mc], 0, 0, 0);
    }

    #pragma unroll
    for (int mc = 0; mc < 4; ++mc) {
        const int c = 64 * w + mc * 16 + l15;
        const float bias = b2f(OB[c]);
        float gs = 0.f, gq = 0.f;
        #pragma unroll
        for (int mn = 0; mn < 4; ++mn) {
            const int nb = n0 + mn * 16 + lh * 4;
            const size_t fi = (size_t)(b * CHN + c) * NSP + nb;
            f32x4 fv;
            if (isf) {
                fv = *(const f32x4*)((const float*)feat + fi);
            } else {
                #pragma unroll
                for (int e = 0; e < 4; ++e) fv[e] = b2f(feat[fi + e]);
            }
            f32x4 out4;
            #pragma unroll
            for (int r = 0; r < 4; ++r) {
                const float v = acc[mn][mc][r] + bias + fv[r];
                out4[r] = v; gs += v; gq += v * v;
            }
            *(f32x4*)(Y + (size_t)(sb * CHN + c) * NSP + nb) = out4;
        }
        #pragma unroll
        for (int off = 1; off < 64; off <<= 1) {
            gs += __shfl_xor(gs, off);
            gq += __shfl_xor(gq, off);
        }
        if (lane == 0) {
            atomicAdd(&stats[(sb * 16 + 4 * w + mc) * 2], gs);
            atomicAdd(&stats[(sb * 16 + 4 * w + mc) * 2 + 1], gq);
        }
    }
}

// ---------------- Kernel 4: group norm apply (in-place, fp32 d_out) ----------------
__global__ __launch_bounds__(256) void k_norm(
    float* __restrict__ out, const float* __restrict__ stats,
    const unsigned short* __restrict__ prm)
{
    const int e0 = (blockIdx.x * 256 + threadIdx.x) * 8;
    const int c = (e0 >> 12) & 255;
    const int sb = e0 >> 20;
    const int s = sb >> 2;
    const int g = c >> 4;
    const float s1 = stats[(sb * 16 + g) * 2];
    const float s2 = stats[(sb * 16 + g) * 2 + 1];
    const float inv = 1.0f / 65536.0f;
    const float mean = s1 * inv;
    const float var = s2 * inv - mean * mean;
    const float rstd = rsqrtf(var + 1e-5f);
    const float gamma = b2f(prm[(s ? 18 : 16) * SL + c]);
    const float beta  = b2f(prm[(s ? 19 : 17) * SL + c]);
    const float a = rstd * gamma;
    const float bb = beta - mean * a;
    f32x4 y0 = *(const f32x4*)(out + e0);
    f32x4 y1 = *(const f32x4*)(out + e0 + 4);
    #pragma unroll
    for (int e = 0; e < 4; ++e) { y0[e] = y0[e] * a + bb; y1[e] = y1[e] * a + bb; }
    *(f32x4*)(out + e0) = y0;
    *(f32x4*)(out + e0 + 4) = y1;
}

extern "C" void kernel_launch(void* const* d_in, const int* in_sizes, int n_in,
                              void* d_out, int out_size, void* d_ws, size_t ws_size,
                              hipStream_t stream)
{
    const unsigned short* feat_a = (const unsigned short*)d_in[0];
    const unsigned short* feat_b = (const unsigned short*)d_in[1];

    char* ws = (char*)d_ws;
    unsigned short* Qp = (unsigned short*)(ws);
    unsigned short* Kp = (unsigned short*)(ws + (4u << 20));
    unsigned short* Vp = (unsigned short*)(ws + (8u << 20));
    unsigned short* Op = (unsigned short*)(ws + (12u << 20));
    float* stats = (float*)(ws + (16u << 20));
    unsigned short* prm = (unsigned short*)(ws + (16u << 20) + 65536);

    P20 ptrs;
    for (int i = 0; i < 20; ++i) ptrs.p[i] = d_in[2 + i];

    float* out = (float*)d_out;

    hipMemsetAsync(stats, 0, 256 * sizeof(float), stream);
    k_conv<<<20, 256, 0, stream>>>(ptrs, feat_a, prm);
    k_proj<<<dim3(64, 8), 256, 0, stream>>>(feat_a, feat_b, prm, Qp, Kp, Vp);
    k_attn<<<dim3(64, 32), 128, 0, stream>>>(Qp, Kp, Vp, Op);
    k_out<<<dim3(64, 8), 256, 0, stream>>>(feat_a, feat_b, prm, Op, out, stats);
    k_norm<<<4096, 256, 0, stream>>>(out, stats, prm);
}

// Round 9
// 367.564 us; speedup vs baseline: 1.6301x; 1.0115x over previous
//
#include <hip/hip_runtime.h>

typedef __attribute__((ext_vector_type(8))) short short8;
typedef __attribute__((ext_vector_type(8))) unsigned short u16x8;
typedef __attribute__((ext_vector_type(4))) unsigned short u16x4;
typedef __attribute__((ext_vector_type(4))) float f32x4;
typedef __attribute__((ext_vector_type(16))) float f32x16;

#define NB 4
#define CHN 256
#define NSP 4096
#define PROJD 64
#define NH 4
#define HD 16
#define SL 16384
#define QSCALE 0.36067376022224085f  // SCALE(0.25) * log2(e)
#define FMAX 16.0f                   // fixed softmax max (log2 domain)

__device__ __forceinline__ float b2f(unsigned short u) {
    union { unsigned ui; float f; } x; x.ui = ((unsigned)u) << 16; return x.f;
}
__device__ __forceinline__ unsigned short f2b(float f) {
    union { float f; unsigned ui; } x; x.f = f;
    unsigned r = x.ui + 0x7fffu + ((x.ui >> 16) & 1u);
    return (unsigned short)(r >> 16);
}
__device__ __forceinline__ unsigned cvtpk(float lo, float hi) {
    unsigned r;
    asm("v_cvt_pk_bf16_f32 %0, %1, %2" : "=v"(r) : "v"(lo), "v"(hi));
    return r;
}
__device__ __forceinline__ void plswap(unsigned &a, unsigned &b) {
    asm volatile("v_permlane32_swap_b32 %0, %1" : "+v"(a), "+v"(b));
}
__device__ __forceinline__ short8 mk8(unsigned a, unsigned b, unsigned c, unsigned d) {
    union { unsigned u[4]; short8 v; } x;
    x.u[0] = a; x.u[1] = b; x.u[2] = c; x.u[3] = d;
    return x.v;
}

// Detect underlying dtype of feat buffer: returns 1 if fp32, 0 if bf16.
__device__ __forceinline__ int detect_f32(const unsigned short* fa) {
    const int t = threadIdx.x;
    __shared__ int sflag;
    if (t < 64) {
        int wild = 0;
        #pragma unroll
        for (int e = 0; e < 8; ++e) {
            unsigned short u = fa[(t * 8 + e) * 2];
            int ex = (u >> 7) & 0xFF;
            if (ex != 0 && (ex < 0x6E || ex > 0x8A)) wild++;
        }
        #pragma unroll
        for (int off = 1; off < 64; off <<= 1) wild += __shfl_xor(wild, off);
        if (t == 0) sflag = (wild > 64) ? 1 : 0;
    }
    __syncthreads();
    return sflag;
}

struct P20 { const void* p[20]; };

// ---------------- Kernel 0: canonicalize the 20 param tensors to bf16 slots ----------------
__global__ __launch_bounds__(256) void k_conv(P20 ptrs, const unsigned short* feat_a,
                                              unsigned short* dst) {
    const int isf = detect_f32(feat_a);
    const int id = blockIdx.x;
    const int sizes[20] = {16384,64,16384,64,16384,64,16384,64,16384,64,16384,64,
                           16384,256,16384,256,256,256,256,256};
    const int n = sizes[id];
    unsigned short* o = dst + id * SL;
    if (isf) {
        const float* s = (const float*)ptrs.p[id];
        for (int i = threadIdx.x; i < n; i += 256) o[i] = f2b(s[i]);
    } else {
        const unsigned short* s = (const unsigned short*)ptrs.p[id];
        for (int i = threadIdx.x; i < n; i += 256) o[i] = s[i];
    }
}

// ---------------- Kernel 1: QKV projections ----------------
__global__ __launch_bounds__(256) void k_proj(
    const unsigned short* __restrict__ feat_a, const unsigned short* __restrict__ feat_b,
    const unsigned short* __restrict__ prm,
    unsigned short* __restrict__ Qp, unsigned short* __restrict__ Kp,
    unsigned short* __restrict__ Vp)
{
    const int isf = detect_f32(feat_a);
    const int f = blockIdx.y >> 2;
    const int b = blockIdx.y & 3;
    const int n0 = blockIdx.x * 64;
    const unsigned short* feat = f ? feat_b : feat_a;
    const unsigned short* wq  = prm + (f ? 6 : 0) * SL;
    const unsigned short* biq = prm + (f ? 7 : 1) * SL;
    const unsigned short* wk  = prm + (f ? 2 : 8) * SL;
    const unsigned short* bik = prm + (f ? 3 : 9) * SL;
    const unsigned short* wv  = prm + (f ? 4 : 10) * SL;
    const unsigned short* biv = prm + (f ? 5 : 11) * SL;
    const int sq = f, skv = 1 - f;

    __shared__ unsigned short lds[64 * 40];   // feat^T tile [64 n][32 c], row stride 40 shorts
    const int t = threadIdx.x;
    const int lane = t & 63, w = t >> 6;

    f32x4 acc[12];
    #pragma unroll
    for (int i = 0; i < 12; ++i)
        #pragma unroll
        for (int r = 0; r < 4; ++r) acc[i][r] = 0.f;

    for (int c0 = 0; c0 < CHN; c0 += 32) {
        __syncthreads();
        {
            const int cc = t >> 3, nn = (t & 7) * 8;
            const size_t base = (size_t)(b * CHN + c0 + cc) * NSP + n0 + nn;
            if (isf) {
                const float* ff = (const float*)feat;
                f32x4 v0 = *(const f32x4*)(ff + base);
                f32x4 v1 = *(const f32x4*)(ff + base + 4);
                #pragma unroll
                for (int e = 0; e < 4; ++e) {
                    lds[(nn + e) * 40 + cc] = f2b(v0[e]);
                    lds[(nn + 4 + e) * 40 + cc] = f2b(v1[e]);
                }
            } else {
                u16x8 v = *(const u16x8*)(feat + base);
                #pragma unroll
                for (int e = 0; e < 8; ++e) lds[(nn + e) * 40 + cc] = v[e];
            }
        }
        __syncthreads();
        short8 af = *(const short8*)&lds[(16 * w + (lane & 15)) * 40 + (lane >> 4) * 8];
        #pragma unroll
        for (int mp = 0; mp < 12; ++mp) {
            const unsigned short* W = mp < 4 ? wq : (mp < 8 ? wk : wv);
            const int prow = (mp & 3) * 16 + (lane & 15);
            short8 bf = *(const short8*)(W + prow * CHN + c0 + (lane >> 4) * 8);
            acc[mp] = __builtin_amdgcn_mfma_f32_16x16x32_bf16(af, bf, acc[mp], 0, 0, 0);
        }
    }

    #pragma unroll
    for (int mp = 0; mp < 12; ++mp) {
        const unsigned short* Bi = mp < 4 ? biq : (mp < 8 ? bik : biv);
        const int hh = mp & 3, d = lane & 15;
        const float bias = b2f(Bi[hh * 16 + d]);
        if (mp < 8) {
            #pragma unroll
            for (int r = 0; r < 4; ++r) {
                const int nrow = n0 + 16 * w + (lane >> 4) * 4 + r;
                float val = acc[mp][r] + bias;
                if (mp < 4) {
                    val *= QSCALE;
                    Qp[(((sq * NB + b) * NH + hh) * NSP + nrow) * HD + d] = f2b(val);
                } else {
                    Kp[(((skv * NB + b) * NH + hh) * NSP + nrow) * HD + d] = f2b(val);
                }
            }
        } else {
            // V^T (d-major) write: 4 consecutive n per lane -> one 8B store
            const int nrow0 = n0 + 16 * w + (lane >> 4) * 4;
            u16x4 pk;
            #pragma unroll
            for (int r = 0; r < 4; ++r) pk[r] = f2b(acc[mp][r] + bias);
            *(u16x4*)(Vp + ((size_t)((skv * NB + b) * NH + hh) * HD + d) * NSP + nrow0) = pk;
        }
    }
}

// ---------------- Kernel 2: flash cross-attention ----------------
// Fixed-max softmax (m=16 folded into QK^T C-in), denominator via all-ones PV
// column (n=16). XCD-aware 1-D grid: all 64 i-blocks of an sbh (and exactly
// 4 sbh = 2MB K/V) pin to one XCD -> K/V re-reads are L2-resident.
// grid: 2048 blocks, 128 thr = 2 waves x 32 queries.
__global__ __launch_bounds__(128) void k_attn(
    const unsigned short* __restrict__ Qp,
    const unsigned short* __restrict__ Kp,
    const unsigned short* __restrict__ Vp,
    unsigned short* __restrict__ Op)
{
    const int bid = blockIdx.x;
    const int xcd = bid & 7, slot = bid >> 3;
    const int sbh = xcd * 4 + (slot >> 6);   // 4 sbh per XCD
    const int i0 = (slot & 63) * 64;         // 64 i-tiles of 64 q
    const unsigned short* qb = Qp + sbh * (NSP * HD);
    const unsigned short* kb = Kp + sbh * (NSP * HD);
    const unsigned short* vb = Vp + sbh * (NSP * HD);
    const int t = threadIdx.x, lane = t & 63, w = t >> 6;
    const int lo5 = lane & 31, hi = lane >> 5;
    const int iw = i0 + 32 * w;
    const int dd = lo5 & 15;

    // Q B-fragment: B[k=d=8hi+e][n=q=lo5]
    short8 qf = *(const short8*)(qb + (iw + lo5) * HD + hi * 8);
    const unsigned short* vrow = vb + (size_t)dd * NSP;
    const bool vload = lo5 < 16;
    const unsigned one2 = 0x3f803f80u;   // bf16 1.0 pair
    const short8 vcst = (lo5 == 16) ? mk8(one2, one2, one2, one2) : mk8(0u, 0u, 0u, 0u);

    f32x16 o, cinit;
    #pragma unroll
    for (int r = 0; r < 16; ++r) { o[r] = 0.f; cinit[r] = -FMAX; }

    #pragma unroll 2
    for (int jt = 0; jt < 128; ++jt) {
        const int j0 = jt * 32;
        // K A-fragment from global (L2-resident): A[m=j=lo5][k=d=8hi+e]
        short8 kf = *(const short8*)(kb + (j0 + lo5) * HD + hi * 8);
        // V B-fragments: B[k=j][n=dd] for lo5<16; ones column at n=16
        short8 vf0 = vcst, vf1 = vcst;
        if (vload) {
            vf0 = *(const short8*)(vrow + j0 + hi * 8);
            vf1 = *(const short8*)(vrow + j0 + 16 + hi * 8);
        }

        // st = K·Q - FMAX (fixed max folded into C-in)
        f32x16 st = __builtin_amdgcn_mfma_f32_32x32x16_bf16(kf, qf, cinit, 0, 0, 0);

        float p[16];
        #pragma unroll
        for (int r = 0; r < 16; ++r) p[r] = exp2f(st[r]);

        // pack P (S^T C/D layout) into PV A-fragments via cvt_pk + permlane32_swap
        unsigned w0 = cvtpk(p[0], p[1]),  w1 = cvtpk(p[2], p[3]);
        unsigned w2 = cvtpk(p[4], p[5]),  w3 = cvtpk(p[6], p[7]);
        plswap(w0, w2); plswap(w1, w3);
        unsigned w4 = cvtpk(p[8], p[9]),  w5 = cvtpk(p[10], p[11]);
        unsigned w6 = cvtpk(p[12], p[13]), w7 = cvtpk(p[14], p[15]);
        plswap(w4, w6); plswap(w5, w7);
        short8 pa0 = mk8(w0, w1, w2, w3);
        short8 pa1 = mk8(w4, w5, w6, w7);

        o = __builtin_amdgcn_mfma_f32_32x32x16_bf16(pa0, vf0, o, 0, 0, 0);
        o = __builtin_amdgcn_mfma_f32_32x32x16_bf16(pa1, vf1, o, 0, 0, 0);
    }

    // denominator for query row crow(r,hi) sits in lane (hi*32+16), reg r
    float rr[16];
    #pragma unroll
    for (int r = 0; r < 16; ++r) rr[r] = __shfl(o[r], (hi << 5) + 16);

    const int sb = sbh >> 2, h = sbh & 3;
    if (lo5 < 16) {
        #pragma unroll
        for (int r = 0; r < 16; ++r) {
            const int irow = iw + (r & 3) + 8 * (r >> 2) + 4 * hi;
            Op[(sb * NSP + irow) * PROJD + h * HD + dd] = f2b(o[r] / rr[r]);
        }
    }
}

// ---------------- Kernel 3: out-projection + residual + group stats (fp32 out) ----------------
// A = Op tile (m = spatial n), B = OW (n-dim = channel c) -> rows are 4
// consecutive n per lane: f32x4 residual loads + f32x4 Y stores.
// grid: (64 n-tiles of 64, 8 sb), 256 threads = 4 waves (wave w: 64 channels)
__global__ __launch_bounds__(256) void k_out(
    const unsigned short* __restrict__ feat_a, const unsigned short* __restrict__ feat_b,
    const unsigned short* __restrict__ prm,
    const unsigned short* __restrict__ Op,
    float* __restrict__ Y, float* __restrict__ stats)
{
    const int isf = detect_f32(feat_a);
    const int sb = blockIdx.y;
    const int s = sb >> 2, b = sb & 3;
    const int n0 = blockIdx.x * 64;
    const unsigned short* feat = s ? feat_b : feat_a;
    const unsigned short* OW = prm + (s ? 14 : 12) * SL;
    const unsigned short* OB = prm + (s ? 15 : 13) * SL;
    const int t = threadIdx.x, lane = t & 63, w = t >> 6;
    const unsigned short* ob = Op + (size_t)sb * (NSP * PROJD);
    const int l15 = lane & 15, lh = lane >> 4;

    f32x4 acc[4][4];   // [mn][mc]
    #pragma unroll
    for (int i = 0; i < 4; ++i)
        #pragma unroll
        for (int j = 0; j < 4; ++j)
            #pragma unroll
            for (int r = 0; r < 4; ++r) acc[i][j][r] = 0.f;

    #pragma unroll
    for (int kc = 0; kc < PROJD; kc += 32) {
        short8 af[4], bf[4];
        #pragma unroll
        for (int mn = 0; mn < 4; ++mn)
            af[mn] = *(const short8*)(ob + (n0 + mn * 16 + l15) * PROJD + kc + lh * 8);
        #pragma unroll
        for (int mc = 0; mc < 4; ++mc)
            bf[mc] = *(const short8*)(OW + (64 * w + mc * 16 + l15) * PROJD + kc + lh * 8);
        #pragma unroll
        for (int mn = 0; mn < 4; ++mn)
            #pragma unroll
            for (int mc = 0; mc < 4; ++mc)
                acc[mn][mc] = __builtin_amdgcn_mfma_f32_16x16x32_bf16(af[mn], bf[mc], acc[mn][mc], 0, 0, 0);
    }

    #pragma unroll
    for (int mc = 0; mc < 4; ++mc) {
        const int c = 64 * w + mc * 16 + l15;
        const float bias = b2f(OB[c]);
        float gs = 0.f, gq = 0.f;
        #pragma unroll
        for (int mn = 0; mn < 4; ++mn) {
            const int nb = n0 + mn * 16 + lh * 4;
            const size_t fi = (size_t)(b * CHN + c) * NSP + nb;
            f32x4 fv;
            if (isf) {
                fv = *(const f32x4*)((const float*)feat + fi);
            } else {
                #pragma unroll
                for (int e = 0; e < 4; ++e) fv[e] = b2f(feat[fi + e]);
            }
            f32x4 out4;
            #pragma unroll
            for (int r = 0; r < 4; ++r) {
                const float v = acc[mn][mc][r] + bias + fv[r];
                out4[r] = v; gs += v; gq += v * v;
            }
            *(f32x4*)(Y + (size_t)(sb * CHN + c) * NSP + nb) = out4;
        }
        #pragma unroll
        for (int off = 1; off < 64; off <<= 1) {
            gs += __shfl_xor(gs, off);
            gq += __shfl_xor(gq, off);
        }
        if (lane == 0) {
            atomicAdd(&stats[(sb * 16 + 4 * w + mc) * 2], gs);
            atomicAdd(&stats[(sb * 16 + 4 * w + mc) * 2 + 1], gq);
        }
    }
}

// ---------------- Kernel 4: group norm apply (in-place, fp32 d_out) ----------------
__global__ __launch_bounds__(256) void k_norm(
    float* __restrict__ out, const float* __restrict__ stats,
    const unsigned short* __restrict__ prm)
{
    const int e0 = (blockIdx.x * 256 + threadIdx.x) * 8;
    const int c = (e0 >> 12) & 255;
    const int sb = e0 >> 20;
    const int s = sb >> 2;
    const int g = c >> 4;
    const float s1 = stats[(sb * 16 + g) * 2];
    const float s2 = stats[(sb * 16 + g) * 2 + 1];
    const float inv = 1.0f / 65536.0f;
    const float mean = s1 * inv;
    const float var = s2 * inv - mean * mean;
    const float rstd = rsqrtf(var + 1e-5f);
    const float gamma = b2f(prm[(s ? 18 : 16) * SL + c]);
    const float beta  = b2f(prm[(s ? 19 : 17) * SL + c]);
    const float a = rstd * gamma;
    const float bb = beta - mean * a;
    f32x4 y0 = *(const f32x4*)(out + e0);
    f32x4 y1 = *(const f32x4*)(out + e0 + 4);
    #pragma unroll
    for (int e = 0; e < 4; ++e) { y0[e] = y0[e] * a + bb; y1[e] = y1[e] * a + bb; }
    *(f32x4*)(out + e0) = y0;
    *(f32x4*)(out + e0 + 4) = y1;
}

extern "C" void kernel_launch(void* const* d_in, const int* in_sizes, int n_in,
                              void* d_out, int out_size, void* d_ws, size_t ws_size,
                              hipStream_t stream)
{
    const unsigned short* feat_a = (const unsigned short*)d_in[0];
    const unsigned short* feat_b = (const unsigned short*)d_in[1];

    char* ws = (char*)d_ws;
    unsigned short* Qp = (unsigned short*)(ws);
    unsigned short* Kp = (unsigned short*)(ws + (4u << 20));
    unsigned short* Vp = (unsigned short*)(ws + (8u << 20));
    unsigned short* Op = (unsigned short*)(ws + (12u << 20));
    float* stats = (float*)(ws + (16u << 20));
    unsigned short* prm = (unsigned short*)(ws + (16u << 20) + 65536);

    P20 ptrs;
    for (int i = 0; i < 20; ++i) ptrs.p[i] = d_in[2 + i];

    float* out = (float*)d_out;

    hipMemsetAsync(stats, 0, 256 * sizeof(float), stream);
    k_conv<<<20, 256, 0, stream>>>(ptrs, feat_a, prm);
    k_proj<<<dim3(64, 8), 256, 0, stream>>>(feat_a, feat_b, prm, Qp, Kp, Vp);
    k_attn<<<2048, 128, 0, stream>>>(Qp, Kp, Vp, Op);
    k_out<<<dim3(64, 8), 256, 0, stream>>>(feat_a, feat_b, prm, Op, out, stats);
    k_norm<<<4096, 256, 0, stream>>>(out, stats, prm);
}